// Round 1
// baseline (431.079 us; speedup 1.0000x reference)
//
#include <hip/hip_runtime.h>

// EMA with bias correction along last axis.
// x: (32, 256, 8192) fp32  ->  out same shape.
// y[t] = 0.99*y[t-1] + 0.01*x[t], y[-1]=0 ; out[t] = y[t] / (1 - 0.99^(t+1))
//
// One 256-thread block per row (8192 rows). Chunked scan:
//   stage row into LDS (XOR-swizzled, all accesses 2-way/bank = free),
//   per-thread 32-elem sequential scan in registers,
//   Kogge-Stone shuffle carry scan with constexpr decay powers,
//   4-wave LDS combine, epilogue + bias correction, coalesced store via LDS.

namespace {

constexpr int T = 8192;
constexpr int BLOCK = 256;
constexpr int CHUNK = T / BLOCK;   // 32
constexpr int NWAVE = BLOCK / 64;  // 4
constexpr int VECS = T / (4 * BLOCK);  // 8 float4s per thread

__device__ __forceinline__ int sw(int p) { return p ^ ((p >> 5) & 31); }

__global__ __launch_bounds__(BLOCK) void ema_kernel(const float* __restrict__ x,
                                                    float* __restrict__ out) {
  __shared__ float sm[T];
  __shared__ float smW[NWAVE];

  const int tid = threadIdx.x;
  const long long base = (long long)blockIdx.x * (long long)T;

  // ---- stage in: coalesced float4 loads, swizzled scalar LDS writes ----
  const float4* xv = reinterpret_cast<const float4*>(x + base);
#pragma unroll
  for (int k = 0; k < VECS; ++k) {
    const int u = tid + BLOCK * k;
    const float4 v = xv[u];
    const int p = 4 * u;
    sm[sw(p + 0)] = v.x;
    sm[sw(p + 1)] = v.y;
    sm[sw(p + 2)] = v.z;
    sm[sw(p + 3)] = v.w;
  }
  __syncthreads();

  constexpr float A1 = 0.99f, M = 0.01f;
  constexpr float A2 = A1 * A1;
  constexpr float A4 = A2 * A2;
  constexpr float A8 = A4 * A4;
  constexpr float A16 = A8 * A8;
  constexpr float A32 = A16 * A16;       // decay across one CHUNK
  constexpr float A64 = A32 * A32;
  constexpr float A128 = A64 * A64;
  constexpr float A256 = A128 * A128;
  constexpr float A512 = A256 * A256;
  constexpr float A1024 = A512 * A512;
  constexpr float A2048 = A1024 * A1024; // decay across one wave (64 chunks)
  constexpr float A4096 = A2048 * A2048;

  // ---- per-thread sequential scan of its contiguous chunk ----
  const int cbase = tid * CHUNK;
  float acc[CHUNK];
  float run = 0.0f;
#pragma unroll
  for (int e = 0; e < CHUNK; ++e) {
    run = fmaf(run, A1, M * sm[sw(cbase + e)]);
    acc[e] = run;
  }

  const int lane = tid & 63;
  const int w = tid >> 6;

  // ---- Kogge-Stone inclusive scan of chunk-finals across the wave ----
  // S_j = sum_{k<=j in wave} A32^(j-k) * pf_k
  float S = run;
  {
    float t;
    t = __shfl_up(S, 1, 64);  if (lane >= 1)  S = fmaf(t, A32,   S);
    t = __shfl_up(S, 2, 64);  if (lane >= 2)  S = fmaf(t, A64,   S);
    t = __shfl_up(S, 4, 64);  if (lane >= 4)  S = fmaf(t, A128,  S);
    t = __shfl_up(S, 8, 64);  if (lane >= 8)  S = fmaf(t, A256,  S);
    t = __shfl_up(S, 16, 64); if (lane >= 16) S = fmaf(t, A512,  S);
    t = __shfl_up(S, 32, 64); if (lane >= 32) S = fmaf(t, A1024, S);
  }
  if (lane == 63) smW[w] = S;        // wave total W_w
  const float Sprev = __shfl_up(S, 1, 64);
  __syncthreads();

  // cross-wave prefix: Q_w = sum_{v<w} A2048^(w-1-v) * W_v
  float Q = 0.0f;
#pragma unroll
  for (int v = 0; v < NWAVE - 1; ++v) {
    if (v < w) Q = fmaf(Q, A2048, smW[v]);
  }

  // Dlane = A32^lane (exact binary decomposition, no transcendentals)
  float Dlane = 1.0f;
  if (lane & 1)  Dlane *= A32;
  if (lane & 2)  Dlane *= A64;
  if (lane & 4)  Dlane *= A128;
  if (lane & 8)  Dlane *= A256;
  if (lane & 16) Dlane *= A512;
  if (lane & 32) Dlane *= A1024;

  // carry = y[cbase - 1] = G_{j-1}
  const float carry = (lane ? Sprev : 0.0f) + Dlane * Q;

  // Pt = 0.99^(32*tid)
  float Pt = 1.0f;
  if (tid & 1)   Pt *= A32;
  if (tid & 2)   Pt *= A64;
  if (tid & 4)   Pt *= A128;
  if (tid & 8)   Pt *= A256;
  if (tid & 16)  Pt *= A512;
  if (tid & 32)  Pt *= A1024;
  if (tid & 64)  Pt *= A2048;
  if (tid & 128) Pt *= A4096;

  // ---- epilogue: add carry, bias-correct, write back to LDS ----
  float pw = 1.0f;
#pragma unroll
  for (int e = 0; e < CHUNK; ++e) {
    pw *= A1;                               // 0.99^(e+1)
    Pt *= A1;                               // 0.99^(t+1), t = cbase+e
    const float yv = fmaf(carry, pw, acc[e]);
    const float corr = __builtin_amdgcn_rcpf(1.0f - Pt);
    sm[sw(cbase + e)] = yv * corr;
  }
  __syncthreads();

  // ---- stage out: swizzled scalar LDS reads, coalesced float4 stores ----
  float4* ov = reinterpret_cast<float4*>(out + base);
#pragma unroll
  for (int k = 0; k < VECS; ++k) {
    const int u = tid + BLOCK * k;
    const int p = 4 * u;
    float4 v;
    v.x = sm[sw(p + 0)];
    v.y = sm[sw(p + 1)];
    v.z = sm[sw(p + 2)];
    v.w = sm[sw(p + 3)];
    ov[u] = v;
  }
}

}  // namespace

extern "C" void kernel_launch(void* const* d_in, const int* in_sizes, int n_in,
                              void* d_out, int out_size, void* d_ws, size_t ws_size,
                              hipStream_t stream) {
  const float* x = (const float*)d_in[0];
  float* out = (float*)d_out;
  const int rows = in_sizes[0] / T;  // 32*256 = 8192
  ema_kernel<<<dim3(rows), dim3(BLOCK), 0, stream>>>(x, out);
}